// Round 1
// baseline (281.746 us; speedup 1.0000x reference)
//
#include <hip/hip_runtime.h>
#include <math.h>

#define B_ 2
#define C_ 256
#define H_ 64
#define W_ 96
#define L_ (H_*W_)          // 6144
#define NH_ 8
#define NP_ 16
#define HD_ 32
#define NTOT (B_*L_)        // 12288
#define CO_ALL 656          // 256 value + 16 size + 256 anchor + 128 att
#define CO_PAD 704          // padded to 11*64
#define RAW_CH 400          // size(16) + anchor(256) + att(128)

// ---- workspace layout (floats) ----
#define OFF_WALL 0                         // 704*256 = 180224
#define OFF_BALL 180224                    // 656        -> 180880
#define OFF_MEMT 180880                    // B*L*C = 3145728 -> 3326608
#define OFF_RAW  3326608                   // B*400*L = 4915200 -> 8241808 (shared with MID)
#define OFF_MID  3326608
#define OFF_PX   8241808                   // B*L*NH*NP = 1572864 -> 9814672
#define OFF_PY   9814672                   // -> 11387536
#define OFF_ATT  11387536                  // -> 12960400  (~51.8 MB total)

__device__ __forceinline__ float sigmoidf_(float x) { return 1.f / (1.f + expf(-x)); }

// Pack the 4 conv weight matrices into one 704x256 matrix (rows >=656 zeroed).
__global__ void pack_w(const float* __restrict__ wv, const float* __restrict__ bv,
                       const float* __restrict__ wsz, const float* __restrict__ bsz,
                       const float* __restrict__ wan, const float* __restrict__ ban,
                       const float* __restrict__ wat, const float* __restrict__ bat,
                       float* __restrict__ wall, float* __restrict__ ball) {
    int o = blockIdx.x;
    int c = threadIdx.x;
    float v = 0.f, bvv = 0.f;
    if (o < 256)      { v = wv [(size_t)o*C_ + c];        bvv = bv [o]; }
    else if (o < 272) { v = wsz[(size_t)(o-256)*C_ + c];  bvv = bsz[o-256]; }
    else if (o < 528) { v = wan[(size_t)(o-272)*C_ + c];  bvv = ban[o-272]; }
    else if (o < 656) { v = wat[(size_t)(o-528)*C_ + c];  bvv = bat[o-528]; }
    wall[(size_t)o*C_ + c] = v;
    if (c == 0 && o < CO_ALL) ball[o] = bvv;
}

// GEMM-A: y[b,o,l] = ball[o] + sum_c wall[o,c]*feat[b,c,l]
// o<256 -> memT[b][l][o] (transposed value tensor), o>=256 -> raw[b][o-256][l]
__global__ __launch_bounds__(256) void gemm_all(const float* __restrict__ feat,
        const float* __restrict__ wall, const float* __restrict__ ball,
        float* __restrict__ memT, float* __restrict__ raw) {
    __shared__ float As[16][65];
    __shared__ float Bs[16][68];
    const int m0 = blockIdx.x * 64;
    const int n0 = blockIdx.y * 64;
    const int b  = n0 / L_;
    const int l0 = n0 % L_;
    const int tid = threadIdx.x;
    const int tx = tid & 15, ty = tid >> 4;
    float acc[4][4] = {};

    const float* fb = feat + (size_t)b * C_ * L_;
    const int am = tid >> 2;            // 0..63
    const int ak = (tid & 3) * 4;       // 0,4,8,12
    const float* aptr = wall + (size_t)(m0 + am) * C_ + ak;
    const int bk = tid >> 4;            // 0..15
    const int bl = (tid & 15) * 4;
    const float* bptr = fb + (size_t)bk * L_ + l0 + bl;

    for (int k0 = 0; k0 < C_; k0 += 16) {
        float4 av = *(const float4*)(aptr + k0);
        As[ak+0][am] = av.x; As[ak+1][am] = av.y;
        As[ak+2][am] = av.z; As[ak+3][am] = av.w;
        float4 bv = *(const float4*)(bptr + (size_t)k0 * L_);
        *(float4*)&Bs[bk][bl] = bv;
        __syncthreads();
        #pragma unroll
        for (int kk = 0; kk < 16; ++kk) {
            float a[4], bb[4];
            #pragma unroll
            for (int i = 0; i < 4; ++i) a[i] = As[kk][ty*4+i];
            #pragma unroll
            for (int j = 0; j < 4; ++j) bb[j] = Bs[kk][tx*4+j];
            #pragma unroll
            for (int i = 0; i < 4; ++i)
                #pragma unroll
                for (int j = 0; j < 4; ++j)
                    acc[i][j] += a[i] * bb[j];
        }
        __syncthreads();
    }

    float bi[4];
    #pragma unroll
    for (int i = 0; i < 4; ++i) {
        int o = m0 + ty*4 + i;
        bi[i] = (o < CO_ALL) ? ball[o] : 0.f;
    }
    if (m0 < 256) {
        const int o = m0 + ty*4;
        #pragma unroll
        for (int j = 0; j < 4; ++j) {
            int l = l0 + tx*4 + j;
            float4 v = make_float4(acc[0][j]+bi[0], acc[1][j]+bi[1],
                                   acc[2][j]+bi[2], acc[3][j]+bi[3]);
            *(float4*)&memT[((size_t)(b*L_ + l))*C_ + o] = v;
        }
    } else {
        #pragma unroll
        for (int i = 0; i < 4; ++i) {
            int o = m0 + ty*4 + i;
            if (o < CO_ALL) {
                int r = o - 256;
                float4 v = make_float4(acc[i][0]+bi[i], acc[i][1]+bi[i],
                                       acc[i][2]+bi[i], acc[i][3]+bi[i]);
                *(float4*)&raw[((size_t)(b*RAW_CH + r))*L_ + l0 + tx*4] = v;
            }
        }
    }
}

// post: sigmoid/clip -> grid coords (px,py in pixels) + softmax attention
// one 16-lane group per (b,l,h); lane = p
__global__ __launch_bounds__(256) void post_kernel(const float* __restrict__ raw,
        float* __restrict__ px, float* __restrict__ py, float* __restrict__ att) {
    const int tid = threadIdx.x;
    const int p = tid & 15;
    const int g = tid >> 4;
    const long gid = (long)blockIdx.x * 16 + g;   // over B*L*NH, h fastest
    const int h = (int)(gid % NH_);
    const long bl = gid / NH_;
    const int l = (int)(bl % L_);
    const int b = (int)(bl / L_);
    const float* rb = raw + (size_t)b * RAW_CH * L_ + l;

    float sx = fminf(fmaxf(sigmoidf_(rb[(size_t)(h*2+0)*L_]), 0.25f), 0.75f);
    float sy = fminf(fmaxf(sigmoidf_(rb[(size_t)(h*2+1)*L_]), 0.25f), 0.75f);
    float cx = ((l % W_) + 0.5f) / ((float)W_ + 1e-6f);
    float cy = ((l / W_) + 0.5f) / ((float)H_ + 1e-6f);

    float ox = sigmoidf_(rb[(size_t)(16 + h*NP_*2 + p*2 + 0)*L_]);
    float oy = sigmoidf_(rb[(size_t)(16 + h*NP_*2 + p*2 + 1)*L_]);
    float gx = cx - 0.5f*sx + ox*sx;
    float gy = cy - 0.5f*sy + oy*sy;
    gx = fminf(fmaxf(gx, 0.f), 1.f) * (float)(W_-1);
    gy = fminf(fmaxf(gy, 0.f), 1.f) * (float)(H_-1);

    const long base = ((long)(b*L_ + l)*NH_ + h)*NP_ + p;
    px[base] = gx;
    py[base] = gy;

    float a = rb[(size_t)(272 + h*NP_ + p)*L_];
    float m = a;
    #pragma unroll
    for (int d = 8; d >= 1; d >>= 1) m = fmaxf(m, __shfl_xor(m, d, 16));
    float e = expf(a - m);
    float s = e;
    #pragma unroll
    for (int d = 8; d >= 1; d >>= 1) s += __shfl_xor(s, d, 16);
    att[base] = e / s;
}

// sampling + attention-weighted combine
// block: (b,h, 32 l's). wave handles 8 l's; lane: d = lane&31, point-group pg = lane>>5
__global__ __launch_bounds__(256) void sample_kernel(const float* __restrict__ memT,
        const float* __restrict__ px, const float* __restrict__ py,
        const float* __restrict__ att, float* __restrict__ mid) {
    __shared__ float tile[HD_][33];
    const int blk = blockIdx.x;
    const int lt = blk % (L_/32);
    const int rem = blk / (L_/32);
    const int h = rem % NH_;
    const int b = rem / NH_;
    const int l0 = lt * 32;
    const int wave = threadIdx.x >> 6;
    const int lane = threadIdx.x & 63;
    const int d = lane & 31;
    const int pg = lane >> 5;
    const float* vb = memT + (size_t)b * L_ * C_ + h * HD_ + d;

    #pragma unroll
    for (int li = 0; li < 8; ++li) {
        const int l = l0 + wave*8 + li;
        const long pbase = ((long)(b*L_ + l)*NH_ + h)*NP_;
        float acc = 0.f;
        #pragma unroll
        for (int pi = 0; pi < 8; ++pi) {
            const int p = pg + pi*2;
            float gx = px[pbase+p], gy = py[pbase+p], aw = att[pbase+p];
            float x0f = floorf(gx), y0f = floorf(gy);
            float wx = gx - x0f, wy = gy - y0f;
            int x0 = (int)x0f, y0 = (int)y0f;
            int x0i = min(max(x0, 0), W_-1), x1i = min(max(x0+1, 0), W_-1);
            int y0i = min(max(y0, 0), H_-1), y1i = min(max(y0+1, 0), H_-1);
            const float* r0 = vb + (size_t)(y0i*W_)*C_;
            const float* r1 = vb + (size_t)(y1i*W_)*C_;
            float v00 = r0[(size_t)x0i*C_];
            float v01 = r0[(size_t)x1i*C_];
            float v10 = r1[(size_t)x0i*C_];
            float v11 = r1[(size_t)x1i*C_];
            float top = (1.f-wx)*v00 + wx*v01;
            float bot = (1.f-wx)*v10 + wx*v11;
            acc += aw * ((1.f-wy)*top + wy*bot);
        }
        acc += __shfl_down(acc, 32);
        if (pg == 0) tile[d][wave*8 + li] = acc;
    }
    __syncthreads();
    // write mid[b][h*32+d][l0..l0+31], 4 floats per thread
    const int t = threadIdx.x;
    const int dd = t >> 3;
    const int j4 = (t & 7) * 4;
    float4 v;
    v.x = tile[dd][j4+0]; v.y = tile[dd][j4+1];
    v.z = tile[dd][j4+2]; v.w = tile[dd][j4+3];
    *(float4*)&mid[((size_t)(b*C_ + h*HD_ + dd))*L_ + l0 + j4] = v;
}

// GEMM-B: out[b,o,l] = BN( sum_c w_out[o,c] * mid[b,c,l] )
__global__ __launch_bounds__(256) void gemm_out(const float* __restrict__ mid,
        const float* __restrict__ wout,
        const float* __restrict__ gamma, const float* __restrict__ beta,
        const float* __restrict__ mean, const float* __restrict__ var,
        float* __restrict__ out) {
    __shared__ float As[16][65];
    __shared__ float Bs[16][68];
    const int m0 = blockIdx.x * 64;
    const int n0 = blockIdx.y * 64;
    const int b  = n0 / L_;
    const int l0 = n0 % L_;
    const int tid = threadIdx.x;
    const int tx = tid & 15, ty = tid >> 4;
    float acc[4][4] = {};

    const float* fb = mid + (size_t)b * C_ * L_;
    const int am = tid >> 2;
    const int ak = (tid & 3) * 4;
    const float* aptr = wout + (size_t)(m0 + am) * C_ + ak;
    const int bk = tid >> 4;
    const int bl = (tid & 15) * 4;
    const float* bptr = fb + (size_t)bk * L_ + l0 + bl;

    for (int k0 = 0; k0 < C_; k0 += 16) {
        float4 av = *(const float4*)(aptr + k0);
        As[ak+0][am] = av.x; As[ak+1][am] = av.y;
        As[ak+2][am] = av.z; As[ak+3][am] = av.w;
        float4 bv = *(const float4*)(bptr + (size_t)k0 * L_);
        *(float4*)&Bs[bk][bl] = bv;
        __syncthreads();
        #pragma unroll
        for (int kk = 0; kk < 16; ++kk) {
            float a[4], bb[4];
            #pragma unroll
            for (int i = 0; i < 4; ++i) a[i] = As[kk][ty*4+i];
            #pragma unroll
            for (int j = 0; j < 4; ++j) bb[j] = Bs[kk][tx*4+j];
            #pragma unroll
            for (int i = 0; i < 4; ++i)
                #pragma unroll
                for (int j = 0; j < 4; ++j)
                    acc[i][j] += a[i] * bb[j];
        }
        __syncthreads();
    }

    #pragma unroll
    for (int i = 0; i < 4; ++i) {
        int o = m0 + ty*4 + i;
        float sc = gamma[o] * rsqrtf(var[o] + 1e-5f);
        float mn = mean[o], bt = beta[o];
        float4 v = make_float4((acc[i][0]-mn)*sc+bt, (acc[i][1]-mn)*sc+bt,
                               (acc[i][2]-mn)*sc+bt, (acc[i][3]-mn)*sc+bt);
        *(float4*)&out[(size_t)b*C_*L_ + (size_t)o*L_ + l0 + tx*4] = v;
    }
}

extern "C" void kernel_launch(void* const* d_in, const int* in_sizes, int n_in,
                              void* d_out, int out_size, void* d_ws, size_t ws_size,
                              hipStream_t stream) {
    const float* feat     = (const float*)d_in[0];
    const float* w_size   = (const float*)d_in[1];
    const float* b_size   = (const float*)d_in[2];
    const float* w_anchor = (const float*)d_in[3];
    const float* b_anchor = (const float*)d_in[4];
    const float* w_value  = (const float*)d_in[5];
    const float* b_value  = (const float*)d_in[6];
    const float* w_att    = (const float*)d_in[7];
    const float* b_att    = (const float*)d_in[8];
    const float* w_out    = (const float*)d_in[9];
    const float* bn_gamma = (const float*)d_in[10];
    const float* bn_beta  = (const float*)d_in[11];
    const float* bn_mean  = (const float*)d_in[12];
    const float* bn_var   = (const float*)d_in[13];

    float* ws   = (float*)d_ws;
    float* wall = ws + OFF_WALL;
    float* ball = ws + OFF_BALL;
    float* memT = ws + OFF_MEMT;
    float* raw  = ws + OFF_RAW;
    float* mid  = ws + OFF_MID;
    float* px   = ws + OFF_PX;
    float* py   = ws + OFF_PY;
    float* attw = ws + OFF_ATT;

    pack_w<<<dim3(CO_PAD), dim3(256), 0, stream>>>(
        w_value, b_value, w_size, b_size, w_anchor, b_anchor, w_att, b_att, wall, ball);
    gemm_all<<<dim3(CO_PAD/64, NTOT/64), dim3(256), 0, stream>>>(feat, wall, ball, memT, raw);
    post_kernel<<<dim3(B_*L_*NH_/16), dim3(256), 0, stream>>>(raw, px, py, attw);
    sample_kernel<<<dim3(B_*NH_*(L_/32)), dim3(256), 0, stream>>>(memT, px, py, attw, mid);
    gemm_out<<<dim3(C_/64, NTOT/64), dim3(256), 0, stream>>>(
        mid, w_out, bn_gamma, bn_beta, bn_mean, bn_var, (float*)d_out);
}

// Round 2
// 210.031 us; speedup vs baseline: 1.3414x; 1.3414x over previous
//
#include <hip/hip_runtime.h>
#include <math.h>

#define B_ 2
#define C_ 256
#define H_ 64
#define W_ 96
#define L_ (H_*W_)          // 6144
#define NH_ 8
#define NP_ 16
#define HD_ 32
#define NTOT (B_*L_)        // 12288
#define CO_ALL 656          // 256 value + 16 size + 256 anchor + 128 att
#define CO_PAD 768          // padded to 6*128
#define RAW_CH 400          // size(16) + anchor(256) + att(128)

// ---- workspace layout (floats) ----
#define OFF_WALL 0                         // 768*256 = 196608
#define OFF_BALL 196608                    // 768      -> 197376
#define OFF_MEMT 197376                    // B*NH*L*HD = 3145728 -> 3343104
#define OFF_RAW  3343104                   // B*400*L = 4915200 -> 8258304 (shared with MID)
#define OFF_MID  3343104
#define OFF_PX   8258304                   // B*L*NH*NP = 1572864 -> 9831168
#define OFF_PY   9831168                   // -> 11404032
#define OFF_ATT  11404032                  // -> 12976896 (~51.9 MB)

__device__ __forceinline__ float sigmoidf_(float x) { return 1.f / (1.f + expf(-x)); }

// Pack the 4 conv weight matrices into one 768x256 matrix (rows >=656 zeroed).
__global__ void pack_w(const float* __restrict__ wv, const float* __restrict__ bv,
                       const float* __restrict__ wsz, const float* __restrict__ bsz,
                       const float* __restrict__ wan, const float* __restrict__ ban,
                       const float* __restrict__ wat, const float* __restrict__ bat,
                       float* __restrict__ wall, float* __restrict__ ball) {
    int o = blockIdx.x;
    int c = threadIdx.x;
    float v = 0.f, bvv = 0.f;
    if (o < 256)      { v = wv [(size_t)o*C_ + c];        bvv = bv [o]; }
    else if (o < 272) { v = wsz[(size_t)(o-256)*C_ + c];  bvv = bsz[o-256]; }
    else if (o < 528) { v = wan[(size_t)(o-272)*C_ + c];  bvv = ban[o-272]; }
    else if (o < 656) { v = wat[(size_t)(o-528)*C_ + c];  bvv = bat[o-528]; }
    wall[(size_t)o*C_ + c] = v;
    if (c == 0) ball[o] = (o < CO_ALL) ? bvv : 0.f;
}

// GEMM-A: y[b,o,l] = ball[o] + sum_c wall[o,c]*feat[b,c,l]
// o<256 -> memT[b][h][l][d] (head-contiguous value tensor), o>=256 -> raw[b][o-256][l]
// 128x128 tile, 256 threads, 8x8 acc (rows ty*8 contiguous; cols tx*4 and 64+tx*4)
__global__ __launch_bounds__(256) void gemm_all(const float* __restrict__ feat,
        const float* __restrict__ wall, const float* __restrict__ ball,
        float* __restrict__ memT, float* __restrict__ raw) {
    __shared__ float As[16][132];
    __shared__ float Bs[16][132];
    const int m0 = blockIdx.x * 128;
    const int n0 = blockIdx.y * 128;
    const int b  = n0 / L_;
    const int l0 = n0 % L_;
    const int tid = threadIdx.x;
    const int tx = tid & 15, ty = tid >> 4;
    float acc[8][8] = {};

    const float* fb = feat + (size_t)b * C_ * L_;
    const int ar  = tid >> 2;          // 0..63
    const int akq = (tid & 3) * 4;     // 0,4,8,12
    const float* aptr = wall + (size_t)(m0 + ar) * C_ + akq;
    const int bk = tid >> 5;           // 0..7
    const int bl = (tid & 31) * 4;
    const float* bptr = fb + (size_t)bk * L_ + l0 + bl;

    for (int k0 = 0; k0 < C_; k0 += 16) {
        float4 a0 = *(const float4*)(aptr + k0);
        float4 a1 = *(const float4*)(aptr + (size_t)64 * C_ + k0);
        float4 b0 = *(const float4*)(bptr + (size_t)k0 * L_);
        float4 b1 = *(const float4*)(bptr + (size_t)(k0 + 8) * L_);
        As[akq+0][ar] = a0.x; As[akq+1][ar] = a0.y; As[akq+2][ar] = a0.z; As[akq+3][ar] = a0.w;
        As[akq+0][ar+64] = a1.x; As[akq+1][ar+64] = a1.y; As[akq+2][ar+64] = a1.z; As[akq+3][ar+64] = a1.w;
        *(float4*)&Bs[bk][bl] = b0;
        *(float4*)&Bs[bk+8][bl] = b1;
        __syncthreads();
        #pragma unroll
        for (int kk = 0; kk < 16; ++kk) {
            float a[8], bb[8];
            #pragma unroll
            for (int i = 0; i < 8; ++i) a[i] = As[kk][ty*8+i];
            #pragma unroll
            for (int j = 0; j < 4; ++j) { bb[j] = Bs[kk][tx*4+j]; bb[4+j] = Bs[kk][64+tx*4+j]; }
            #pragma unroll
            for (int i = 0; i < 8; ++i)
                #pragma unroll
                for (int j = 0; j < 8; ++j)
                    acc[i][j] += a[i] * bb[j];
        }
        __syncthreads();
    }

    float bi[8];
    #pragma unroll
    for (int i = 0; i < 8; ++i) bi[i] = ball[m0 + ty*8 + i];

    if (m0 < 256) {
        const int o0 = m0 + ty*8;
        const int h  = o0 >> 5;
        const int d0 = o0 & 31;
        #pragma unroll
        for (int j = 0; j < 8; ++j) {
            int l = l0 + (j < 4 ? tx*4 + j : 64 + tx*4 + (j - 4));
            float* dst = memT + (((size_t)(b*NH_ + h) * L_ + l) * HD_ + d0);
            float4 v0 = make_float4(acc[0][j]+bi[0], acc[1][j]+bi[1], acc[2][j]+bi[2], acc[3][j]+bi[3]);
            float4 v1 = make_float4(acc[4][j]+bi[4], acc[5][j]+bi[5], acc[6][j]+bi[6], acc[7][j]+bi[7]);
            *(float4*)dst = v0;
            *(float4*)(dst + 4) = v1;
        }
    } else {
        #pragma unroll
        for (int i = 0; i < 8; ++i) {
            int o = m0 + ty*8 + i;
            if (o < CO_ALL) {
                int r = o - 256;
                float* dst = raw + ((size_t)(b*RAW_CH + r)) * L_ + l0;
                *(float4*)(dst + tx*4) = make_float4(acc[i][0]+bi[i], acc[i][1]+bi[i],
                                                     acc[i][2]+bi[i], acc[i][3]+bi[i]);
                *(float4*)(dst + 64 + tx*4) = make_float4(acc[i][4]+bi[i], acc[i][5]+bi[i],
                                                          acc[i][6]+bi[i], acc[i][7]+bi[i]);
            }
        }
    }
}

// post: sigmoid/clip -> grid coords (px,py in pixels) + softmax attention
// one 16-lane group per (b,l,h); lane = p
__global__ __launch_bounds__(256) void post_kernel(const float* __restrict__ raw,
        float* __restrict__ px, float* __restrict__ py, float* __restrict__ att) {
    const int tid = threadIdx.x;
    const int p = tid & 15;
    const int g = tid >> 4;
    const long gid = (long)blockIdx.x * 16 + g;   // over B*L*NH, h fastest
    const int h = (int)(gid % NH_);
    const long bl = gid / NH_;
    const int l = (int)(bl % L_);
    const int b = (int)(bl / L_);
    const float* rb = raw + (size_t)b * RAW_CH * L_ + l;

    float sx = fminf(fmaxf(sigmoidf_(rb[(size_t)(h*2+0)*L_]), 0.25f), 0.75f);
    float sy = fminf(fmaxf(sigmoidf_(rb[(size_t)(h*2+1)*L_]), 0.25f), 0.75f);
    float cx = ((l % W_) + 0.5f) / ((float)W_ + 1e-6f);
    float cy = ((l / W_) + 0.5f) / ((float)H_ + 1e-6f);

    float ox = sigmoidf_(rb[(size_t)(16 + h*NP_*2 + p*2 + 0)*L_]);
    float oy = sigmoidf_(rb[(size_t)(16 + h*NP_*2 + p*2 + 1)*L_]);
    float gx = cx - 0.5f*sx + ox*sx;
    float gy = cy - 0.5f*sy + oy*sy;
    gx = fminf(fmaxf(gx, 0.f), 1.f) * (float)(W_-1);
    gy = fminf(fmaxf(gy, 0.f), 1.f) * (float)(H_-1);

    const long base = ((long)(b*L_ + l)*NH_ + h)*NP_ + p;
    px[base] = gx;
    py[base] = gy;

    float a = rb[(size_t)(272 + h*NP_ + p)*L_];
    float m = a;
    #pragma unroll
    for (int d = 8; d >= 1; d >>= 1) m = fmaxf(m, __shfl_xor(m, d, 16));
    float e = expf(a - m);
    float s = e;
    #pragma unroll
    for (int d = 8; d >= 1; d >>= 1) s += __shfl_xor(s, d, 16);
    att[base] = e / s;
}

// sampling + attention-weighted combine
// XCD-aware: each XCD owns 2 of the 16 (b,h) pairs -> its two 786KB memT slices stay L2-resident
// block: (b,h, 32 l's). wave handles 8 l's; lane: d = lane&31, point-group pg = lane>>5
__global__ __launch_bounds__(256) void sample_kernel(const float* __restrict__ memT,
        const float* __restrict__ px, const float* __restrict__ py,
        const float* __restrict__ att, float* __restrict__ mid) {
    __shared__ float tile[HD_][33];
    const int blk = blockIdx.x;
    const int xcd = blk & 7;             // dispatch round-robins blockIdx across 8 XCDs
    const int j   = blk >> 3;            // 0..383
    const int half = (j >= (L_/32)) ? 1 : 0;
    const int bh  = xcd * 2 + half;      // 0..15
    const int lt  = j - half * (L_/32);
    const int h = bh & 7;
    const int b = bh >> 3;
    const int l0 = lt * 32;
    const int wave = threadIdx.x >> 6;
    const int lane = threadIdx.x & 63;
    const int d = lane & 31;
    const int pg = lane >> 5;
    const float* vb = memT + (size_t)(b*NH_ + h) * L_ * HD_ + d;

    #pragma unroll
    for (int li = 0; li < 8; ++li) {
        const int l = l0 + wave*8 + li;
        const long pbase = ((long)(b*L_ + l)*NH_ + h)*NP_;
        float acc = 0.f;
        #pragma unroll
        for (int pi = 0; pi < 8; ++pi) {
            const int p = pg + pi*2;
            float gx = px[pbase+p], gy = py[pbase+p], aw = att[pbase+p];
            float x0f = floorf(gx), y0f = floorf(gy);
            float wx = gx - x0f, wy = gy - y0f;
            int x0 = (int)x0f, y0 = (int)y0f;
            int x0i = min(max(x0, 0), W_-1), x1i = min(max(x0+1, 0), W_-1);
            int y0i = min(max(y0, 0), H_-1), y1i = min(max(y0+1, 0), H_-1);
            const float* r0 = vb + (size_t)(y0i*W_)*HD_;
            const float* r1 = vb + (size_t)(y1i*W_)*HD_;
            float v00 = r0[(size_t)x0i*HD_];
            float v01 = r0[(size_t)x1i*HD_];
            float v10 = r1[(size_t)x0i*HD_];
            float v11 = r1[(size_t)x1i*HD_];
            float top = (1.f-wx)*v00 + wx*v01;
            float bot = (1.f-wx)*v10 + wx*v11;
            acc += aw * ((1.f-wy)*top + wy*bot);
        }
        acc += __shfl_down(acc, 32);
        if (pg == 0) tile[d][wave*8 + li] = acc;
    }
    __syncthreads();
    // write mid[b][h*32+d][l0..l0+31], 4 floats per thread
    const int t = threadIdx.x;
    const int dd = t >> 3;
    const int j4 = (t & 7) * 4;
    float4 v;
    v.x = tile[dd][j4+0]; v.y = tile[dd][j4+1];
    v.z = tile[dd][j4+2]; v.w = tile[dd][j4+3];
    *(float4*)&mid[((size_t)(b*C_ + h*HD_ + dd))*L_ + l0 + j4] = v;
}

// GEMM-B: out[b,o,l] = BN( sum_c w_out[o,c] * mid[b,c,l] ), 128x128 tile
__global__ __launch_bounds__(256) void gemm_out(const float* __restrict__ mid,
        const float* __restrict__ wout,
        const float* __restrict__ gamma, const float* __restrict__ beta,
        const float* __restrict__ mean, const float* __restrict__ var,
        float* __restrict__ out) {
    __shared__ float As[16][132];
    __shared__ float Bs[16][132];
    const int m0 = blockIdx.x * 128;
    const int n0 = blockIdx.y * 128;
    const int b  = n0 / L_;
    const int l0 = n0 % L_;
    const int tid = threadIdx.x;
    const int tx = tid & 15, ty = tid >> 4;
    float acc[8][8] = {};

    const float* fb = mid + (size_t)b * C_ * L_;
    const int ar  = tid >> 2;
    const int akq = (tid & 3) * 4;
    const float* aptr = wout + (size_t)(m0 + ar) * C_ + akq;
    const int bk = tid >> 5;
    const int bl = (tid & 31) * 4;
    const float* bptr = fb + (size_t)bk * L_ + l0 + bl;

    for (int k0 = 0; k0 < C_; k0 += 16) {
        float4 a0 = *(const float4*)(aptr + k0);
        float4 a1 = *(const float4*)(aptr + (size_t)64 * C_ + k0);
        float4 b0 = *(const float4*)(bptr + (size_t)k0 * L_);
        float4 b1 = *(const float4*)(bptr + (size_t)(k0 + 8) * L_);
        As[akq+0][ar] = a0.x; As[akq+1][ar] = a0.y; As[akq+2][ar] = a0.z; As[akq+3][ar] = a0.w;
        As[akq+0][ar+64] = a1.x; As[akq+1][ar+64] = a1.y; As[akq+2][ar+64] = a1.z; As[akq+3][ar+64] = a1.w;
        *(float4*)&Bs[bk][bl] = b0;
        *(float4*)&Bs[bk+8][bl] = b1;
        __syncthreads();
        #pragma unroll
        for (int kk = 0; kk < 16; ++kk) {
            float a[8], bb[8];
            #pragma unroll
            for (int i = 0; i < 8; ++i) a[i] = As[kk][ty*8+i];
            #pragma unroll
            for (int j = 0; j < 4; ++j) { bb[j] = Bs[kk][tx*4+j]; bb[4+j] = Bs[kk][64+tx*4+j]; }
            #pragma unroll
            for (int i = 0; i < 8; ++i)
                #pragma unroll
                for (int j = 0; j < 8; ++j)
                    acc[i][j] += a[i] * bb[j];
        }
        __syncthreads();
    }

    #pragma unroll
    for (int i = 0; i < 8; ++i) {
        int o = m0 + ty*8 + i;
        float sc = gamma[o] * rsqrtf(var[o] + 1e-5f);
        float mn = mean[o], bt = beta[o];
        float* dst = out + (size_t)b*C_*L_ + (size_t)o*L_ + l0;
        *(float4*)(dst + tx*4) = make_float4((acc[i][0]-mn)*sc+bt, (acc[i][1]-mn)*sc+bt,
                                             (acc[i][2]-mn)*sc+bt, (acc[i][3]-mn)*sc+bt);
        *(float4*)(dst + 64 + tx*4) = make_float4((acc[i][4]-mn)*sc+bt, (acc[i][5]-mn)*sc+bt,
                                                  (acc[i][6]-mn)*sc+bt, (acc[i][7]-mn)*sc+bt);
    }
}

extern "C" void kernel_launch(void* const* d_in, const int* in_sizes, int n_in,
                              void* d_out, int out_size, void* d_ws, size_t ws_size,
                              hipStream_t stream) {
    const float* feat     = (const float*)d_in[0];
    const float* w_size   = (const float*)d_in[1];
    const float* b_size   = (const float*)d_in[2];
    const float* w_anchor = (const float*)d_in[3];
    const float* b_anchor = (const float*)d_in[4];
    const float* w_value  = (const float*)d_in[5];
    const float* b_value  = (const float*)d_in[6];
    const float* w_att    = (const float*)d_in[7];
    const float* b_att    = (const float*)d_in[8];
    const float* w_out    = (const float*)d_in[9];
    const float* bn_gamma = (const float*)d_in[10];
    const float* bn_beta  = (const float*)d_in[11];
    const float* bn_mean  = (const float*)d_in[12];
    const float* bn_var   = (const float*)d_in[13];

    float* ws   = (float*)d_ws;
    float* wall = ws + OFF_WALL;
    float* ball = ws + OFF_BALL;
    float* memT = ws + OFF_MEMT;
    float* raw  = ws + OFF_RAW;
    float* mid  = ws + OFF_MID;
    float* px   = ws + OFF_PX;
    float* py   = ws + OFF_PY;
    float* attw = ws + OFF_ATT;

    pack_w<<<dim3(CO_PAD), dim3(256), 0, stream>>>(
        w_value, b_value, w_size, b_size, w_anchor, b_anchor, w_att, b_att, wall, ball);
    gemm_all<<<dim3(CO_PAD/128, NTOT/128), dim3(256), 0, stream>>>(feat, wall, ball, memT, raw);
    post_kernel<<<dim3(B_*L_*NH_/16), dim3(256), 0, stream>>>(raw, px, py, attw);
    sample_kernel<<<dim3(B_*NH_*(L_/32)), dim3(256), 0, stream>>>(memT, px, py, attw, mid);
    gemm_out<<<dim3(C_/128, NTOT/128), dim3(256), 0, stream>>>(
        mid, w_out, bn_gamma, bn_beta, bn_mean, bn_var, (float*)d_out);
}

// Round 3
// 161.778 us; speedup vs baseline: 1.7416x; 1.2983x over previous
//
#include <hip/hip_runtime.h>
#include <math.h>

#define B_ 2
#define C_ 256
#define H_ 64
#define W_ 96
#define L_ (H_*W_)          // 6144
#define NH_ 8
#define NP_ 16
#define HD_ 32
#define NTOT (B_*L_)        // 12288
#define CO_ALL 656
#define CO_PAD 768
#define RAW_CH 400
#define LDK 72              // LDS row stride in bf16 elems (64 + 8 pad) = 144B

typedef __attribute__((ext_vector_type(8))) short short8;
typedef __attribute__((ext_vector_type(4))) float f32x4;

// ---- workspace layout (float offsets) ----
#define OFF_WALLBF 0          // 768*256 ushort = 98304 floats
#define OFF_BALL   98304      // 768 floats -> 99072
#define OFF_WOUTBF 99072      // 256*256 ushort = 32768 floats -> 131840
#define OFF_FEATT  131840     // B*L*C ushort = 1572864 floats -> 1704704
#define OFF_MEMT   1704704    // B*NH*L*HD ushort = 1572864 floats -> 3277568
#define OFF_RAW    3277568    // B*400*L floats = 4915200 -> 8192768
#define OFF_MIDT   3277568    // aliases RAW (raw dead after post_kernel)
#define OFF_PX     8192768    // B*L*NH*NP = 1572864 -> 9765632
#define OFF_PY     9765632    // -> 11338496
#define OFF_ATT    11338496   // -> 12911360 (~51.6 MB)

__device__ __forceinline__ float sigmoidf_(float x) { return 1.f / (1.f + expf(-x)); }

__device__ __forceinline__ unsigned short f2bf(float x) {
    union { float f; unsigned int u; } v; v.f = x;
    unsigned int r = (v.u + 0x7fffu + ((v.u >> 16) & 1u)) >> 16;
    return (unsigned short)r;
}
__device__ __forceinline__ float bf2f(unsigned short h) {
    union { unsigned int u; float f; } v; v.u = ((unsigned int)h) << 16;
    return v.f;
}

// Pack weights to bf16: wallbf[768][256], ball[768], woutbf[256][256]
__global__ void pack_w(const float* __restrict__ wv, const float* __restrict__ bv,
                       const float* __restrict__ wsz, const float* __restrict__ bsz,
                       const float* __restrict__ wan, const float* __restrict__ ban,
                       const float* __restrict__ wat, const float* __restrict__ bat,
                       const float* __restrict__ wout,
                       unsigned short* __restrict__ wallbf, float* __restrict__ ball,
                       unsigned short* __restrict__ woutbf) {
    int o = blockIdx.x;
    int c = threadIdx.x;
    if (o < CO_PAD) {
        float v = 0.f, bvv = 0.f;
        if (o < 256)      { v = wv [(size_t)o*C_ + c];        bvv = bv [o]; }
        else if (o < 272) { v = wsz[(size_t)(o-256)*C_ + c];  bvv = bsz[o-256]; }
        else if (o < 528) { v = wan[(size_t)(o-272)*C_ + c];  bvv = ban[o-272]; }
        else if (o < 656) { v = wat[(size_t)(o-528)*C_ + c];  bvv = bat[o-528]; }
        wallbf[(size_t)o*C_ + c] = f2bf(v);
        if (c == 0) ball[o] = (o < CO_ALL) ? bvv : 0.f;
    } else {
        int r = o - CO_PAD;
        woutbf[(size_t)r*C_ + c] = f2bf(wout[(size_t)r*C_ + c]);
    }
}

// feat[b][c][l] f32 -> featT[b][l][c] bf16, 32x32 LDS transpose tiles
__global__ __launch_bounds__(256) void transpose_feat(const float* __restrict__ feat,
                                                      unsigned short* __restrict__ featT) {
    __shared__ unsigned short tile[32][36];
    const int l0 = blockIdx.x * 32;
    const int c0 = blockIdx.y * 32;
    const int b  = blockIdx.z;
    const int t = threadIdx.x;
    {
        const int c = t >> 3, l4 = (t & 7) * 4;
        float4 v = *(const float4*)(feat + ((size_t)b*C_ + c0 + c)*L_ + l0 + l4);
        tile[c][l4+0] = f2bf(v.x); tile[c][l4+1] = f2bf(v.y);
        tile[c][l4+2] = f2bf(v.z); tile[c][l4+3] = f2bf(v.w);
    }
    __syncthreads();
    {
        const int l = t >> 3, c4 = (t & 7) * 4;
        ushort4 v;
        v.x = tile[c4+0][l]; v.y = tile[c4+1][l];
        v.z = tile[c4+2][l]; v.w = tile[c4+3][l];
        *(ushort4*)(featT + ((size_t)(b*L_ + l0 + l))*C_ + c0 + c4) = v;
    }
}

// GEMM-A (MFMA): y[b,o,l] = ball[o] + sum_c wall[o,c]*feat[b,c,l]
// o<256 -> memT[b][h][l][d] bf16 ; o in [256,656) -> raw[b][o-256][l] f32
__global__ __launch_bounds__(256) void gemm_a_mfma(const unsigned short* __restrict__ featT,
        const unsigned short* __restrict__ wallbf, const float* __restrict__ ball,
        unsigned short* __restrict__ memT, float* __restrict__ raw) {
    __shared__ short As[128 * LDK];
    __shared__ short Bs[128 * LDK];
    const int gid = blockIdx.x;          // 576 blocks, XCD-chunked
    const int xcd = gid & 7, j = gid >> 3;
    const int yt = xcd * 12 + j / 6;
    const int xt = j % 6;
    const int m0 = xt * 128;
    const int n0 = yt * 128;
    const int b  = n0 / L_, l0 = n0 % L_;
    const int tid = threadIdx.x;
    const int wid = tid >> 6, lane = tid & 63;
    const int wr = wid >> 1, wc = wid & 1;
    const int fr = lane & 15, fg = lane >> 4;
    f32x4 acc[4][4] = {};

    const unsigned short* fT = featT + ((size_t)(b*L_ + l0)) * C_;
    const int sr = tid >> 1;             // staging row 0..127
    const int sko = (tid & 1) * 32;      // k offset 0/32

    for (int k0 = 0; k0 < C_; k0 += 64) {
        const short8* ga = (const short8*)(wallbf + (size_t)(m0 + sr)*C_ + k0 + sko);
        const short8* gb = (const short8*)(fT + (size_t)sr*C_ + k0 + sko);
        short* la = As + sr*LDK + sko;
        short* lb = Bs + sr*LDK + sko;
        #pragma unroll
        for (int q = 0; q < 4; ++q) {
            *(short8*)(la + q*8) = ga[q];
            *(short8*)(lb + q*8) = gb[q];
        }
        __syncthreads();
        #pragma unroll
        for (int kk = 0; kk < 64; kk += 32) {
            short8 af[4], bfm[4];
            #pragma unroll
            for (int m = 0; m < 4; ++m)
                af[m] = *(const short8*)(As + (wr*64 + m*16 + fr)*LDK + kk + fg*8);
            #pragma unroll
            for (int n = 0; n < 4; ++n)
                bfm[n] = *(const short8*)(Bs + (wc*64 + n*16 + fr)*LDK + kk + fg*8);
            #pragma unroll
            for (int m = 0; m < 4; ++m)
                #pragma unroll
                for (int n = 0; n < 4; ++n)
                    acc[m][n] = __builtin_amdgcn_mfma_f32_16x16x32_bf16(af[m], bfm[n], acc[m][n], 0, 0, 0);
        }
        __syncthreads();
    }

    if (m0 < 256) {  // value path: memT[b][h][l][d] bf16
        #pragma unroll
        for (int m = 0; m < 4; ++m) {
            const int ob = m0 + wr*64 + m*16 + fg*4;
            const int h = ob >> 5, d0 = ob & 31;
            const float b0 = ball[ob], b1 = ball[ob+1], b2 = ball[ob+2], b3 = ball[ob+3];
            #pragma unroll
            for (int n = 0; n < 4; ++n) {
                const int l = l0 + wc*64 + n*16 + fr;
                ushort4 v;
                v.x = f2bf(acc[m][n][0] + b0);
                v.y = f2bf(acc[m][n][1] + b1);
                v.z = f2bf(acc[m][n][2] + b2);
                v.w = f2bf(acc[m][n][3] + b3);
                *(ushort4*)(memT + ((size_t)(b*NH_ + h)*L_ + l)*HD_ + d0) = v;
            }
        }
    } else {         // raw path: raw[b][r][l] f32
        #pragma unroll
        for (int m = 0; m < 4; ++m) {
            const int ob = m0 + wr*64 + m*16 + fg*4;
            #pragma unroll
            for (int n = 0; n < 4; ++n) {
                const int l = l0 + wc*64 + n*16 + fr;
                #pragma unroll
                for (int q = 0; q < 4; ++q) {
                    const int r = ob + q - 256;
                    if (r < RAW_CH)
                        raw[((size_t)(b*RAW_CH + r))*L_ + l] = acc[m][n][q] + ball[ob+q];
                }
            }
        }
    }
}

// post: sigmoid/clip -> pixel coords + softmax attention (one 16-lane group per (b,l,h))
__global__ __launch_bounds__(256) void post_kernel(const float* __restrict__ raw,
        float* __restrict__ px, float* __restrict__ py, float* __restrict__ att) {
    const int tid = threadIdx.x;
    const int p = tid & 15;
    const int g = tid >> 4;
    const long gid = (long)blockIdx.x * 16 + g;
    const int h = (int)(gid % NH_);
    const long bl = gid / NH_;
    const int l = (int)(bl % L_);
    const int b = (int)(bl / L_);
    const float* rb = raw + (size_t)b * RAW_CH * L_ + l;

    float sx = fminf(fmaxf(sigmoidf_(rb[(size_t)(h*2+0)*L_]), 0.25f), 0.75f);
    float sy = fminf(fmaxf(sigmoidf_(rb[(size_t)(h*2+1)*L_]), 0.25f), 0.75f);
    float cx = ((l % W_) + 0.5f) / ((float)W_ + 1e-6f);
    float cy = ((l / W_) + 0.5f) / ((float)H_ + 1e-6f);

    float ox = sigmoidf_(rb[(size_t)(16 + h*NP_*2 + p*2 + 0)*L_]);
    float oy = sigmoidf_(rb[(size_t)(16 + h*NP_*2 + p*2 + 1)*L_]);
    float gx = cx - 0.5f*sx + ox*sx;
    float gy = cy - 0.5f*sy + oy*sy;
    gx = fminf(fmaxf(gx, 0.f), 1.f) * (float)(W_-1);
    gy = fminf(fmaxf(gy, 0.f), 1.f) * (float)(H_-1);

    const long base = ((long)(b*L_ + l)*NH_ + h)*NP_ + p;
    px[base] = gx;
    py[base] = gy;

    float a = rb[(size_t)(272 + h*NP_ + p)*L_];
    float m = a;
    #pragma unroll
    for (int d = 8; d >= 1; d >>= 1) m = fmaxf(m, __shfl_xor(m, d, 16));
    float e = expf(a - m);
    float s = e;
    #pragma unroll
    for (int d = 8; d >= 1; d >>= 1) s += __shfl_xor(s, d, 16);
    att[base] = e / s;
}

// sampling + combine; XCD-aware (each XCD owns 2 of 16 (b,h) pairs)
// writes midT[b][l][c] bf16
__global__ __launch_bounds__(256) void sample_kernel(const unsigned short* __restrict__ memT,
        const float* __restrict__ px, const float* __restrict__ py,
        const float* __restrict__ att, unsigned short* __restrict__ midT) {
    __shared__ float tile[HD_][33];
    const int blk = blockIdx.x;
    const int xcd = blk & 7;
    const int j   = blk >> 3;
    const int half = (j >= (L_/32)) ? 1 : 0;
    const int bh  = xcd * 2 + half;
    const int lt  = j - half * (L_/32);
    const int h = bh & 7;
    const int b = bh >> 3;
    const int l0 = lt * 32;
    const int wave = threadIdx.x >> 6;
    const int lane = threadIdx.x & 63;
    const int d = lane & 31;
    const int pg = lane >> 5;
    const unsigned short* vb = memT + (size_t)(b*NH_ + h) * L_ * HD_ + d;

    #pragma unroll
    for (int li = 0; li < 8; ++li) {
        const int l = l0 + wave*8 + li;
        const long pbase = ((long)(b*L_ + l)*NH_ + h)*NP_;
        float acc = 0.f;
        #pragma unroll
        for (int pi = 0; pi < 8; ++pi) {
            const int p = pg + pi*2;
            float gx = px[pbase+p], gy = py[pbase+p], aw = att[pbase+p];
            float x0f = floorf(gx), y0f = floorf(gy);
            float wx = gx - x0f, wy = gy - y0f;
            int x0 = (int)x0f, y0 = (int)y0f;
            int x0i = min(max(x0, 0), W_-1), x1i = min(max(x0+1, 0), W_-1);
            int y0i = min(max(y0, 0), H_-1), y1i = min(max(y0+1, 0), H_-1);
            const unsigned short* r0 = vb + (size_t)(y0i*W_)*HD_;
            const unsigned short* r1 = vb + (size_t)(y1i*W_)*HD_;
            float v00 = bf2f(r0[(size_t)x0i*HD_]);
            float v01 = bf2f(r0[(size_t)x1i*HD_]);
            float v10 = bf2f(r1[(size_t)x0i*HD_]);
            float v11 = bf2f(r1[(size_t)x1i*HD_]);
            float top = (1.f-wx)*v00 + wx*v01;
            float bot = (1.f-wx)*v10 + wx*v11;
            acc += aw * ((1.f-wy)*top + wy*bot);
        }
        acc += __shfl_down(acc, 32);
        if (pg == 0) tile[d][wave*8 + li] = acc;
    }
    __syncthreads();
    // write midT[b][l][h*32+d4..], 4 bf16 per thread
    const int t = threadIdx.x;
    const int l = t >> 3;
    const int c4 = (t & 7) * 4;
    ushort4 v;
    v.x = f2bf(tile[c4+0][l]); v.y = f2bf(tile[c4+1][l]);
    v.z = f2bf(tile[c4+2][l]); v.w = f2bf(tile[c4+3][l]);
    *(ushort4*)(midT + ((size_t)(b*L_ + l0 + l))*C_ + h*HD_ + c4) = v;
}

// GEMM-B (MFMA): out[b,o,l] = BN( sum_c w_out[o,c] * midT[b,l,c] )
__global__ __launch_bounds__(256) void gemm_b_mfma(const unsigned short* __restrict__ midT,
        const unsigned short* __restrict__ woutbf,
        const float* __restrict__ gamma, const float* __restrict__ beta,
        const float* __restrict__ mean, const float* __restrict__ var,
        float* __restrict__ out) {
    __shared__ short As[128 * LDK];
    __shared__ short Bs[128 * LDK];
    const int gid = blockIdx.x;          // 192 blocks
    const int xcd = gid & 7, j = gid >> 3;
    const int yt = xcd * 12 + j / 2;
    const int xt = j & 1;
    const int m0 = xt * 128;
    const int n0 = yt * 128;
    const int b  = n0 / L_, l0 = n0 % L_;
    const int tid = threadIdx.x;
    const int wid = tid >> 6, lane = tid & 63;
    const int wr = wid >> 1, wc = wid & 1;
    const int fr = lane & 15, fg = lane >> 4;
    f32x4 acc[4][4] = {};

    const unsigned short* mT = midT + ((size_t)(b*L_ + l0)) * C_;
    const int sr = tid >> 1;
    const int sko = (tid & 1) * 32;

    for (int k0 = 0; k0 < C_; k0 += 64) {
        const short8* ga = (const short8*)(woutbf + (size_t)(m0 + sr)*C_ + k0 + sko);
        const short8* gb = (const short8*)(mT + (size_t)sr*C_ + k0 + sko);
        short* la = As + sr*LDK + sko;
        short* lb = Bs + sr*LDK + sko;
        #pragma unroll
        for (int q = 0; q < 4; ++q) {
            *(short8*)(la + q*8) = ga[q];
            *(short8*)(lb + q*8) = gb[q];
        }
        __syncthreads();
        #pragma unroll
        for (int kk = 0; kk < 64; kk += 32) {
            short8 af[4], bfm[4];
            #pragma unroll
            for (int m = 0; m < 4; ++m)
                af[m] = *(const short8*)(As + (wr*64 + m*16 + fr)*LDK + kk + fg*8);
            #pragma unroll
            for (int n = 0; n < 4; ++n)
                bfm[n] = *(const short8*)(Bs + (wc*64 + n*16 + fr)*LDK + kk + fg*8);
            #pragma unroll
            for (int m = 0; m < 4; ++m)
                #pragma unroll
                for (int n = 0; n < 4; ++n)
                    acc[m][n] = __builtin_amdgcn_mfma_f32_16x16x32_bf16(af[m], bfm[n], acc[m][n], 0, 0, 0);
        }
        __syncthreads();
    }

    #pragma unroll
    for (int m = 0; m < 4; ++m) {
        const int ob = m0 + wr*64 + m*16 + fg*4;
        float sc[4], mn[4], bt[4];
        #pragma unroll
        for (int q = 0; q < 4; ++q) {
            const int o = ob + q;
            sc[q] = gamma[o] * rsqrtf(var[o] + 1e-5f);
            mn[q] = mean[o]; bt[q] = beta[o];
        }
        #pragma unroll
        for (int n = 0; n < 4; ++n) {
            const int l = l0 + wc*64 + n*16 + fr;
            #pragma unroll
            for (int q = 0; q < 4; ++q)
                out[(size_t)b*C_*L_ + (size_t)(ob+q)*L_ + l] = (acc[m][n][q] - mn[q])*sc[q] + bt[q];
        }
    }
}

extern "C" void kernel_launch(void* const* d_in, const int* in_sizes, int n_in,
                              void* d_out, int out_size, void* d_ws, size_t ws_size,
                              hipStream_t stream) {
    const float* feat     = (const float*)d_in[0];
    const float* w_size   = (const float*)d_in[1];
    const float* b_size   = (const float*)d_in[2];
    const float* w_anchor = (const float*)d_in[3];
    const float* b_anchor = (const float*)d_in[4];
    const float* w_value  = (const float*)d_in[5];
    const float* b_value  = (const float*)d_in[6];
    const float* w_att    = (const float*)d_in[7];
    const float* b_att    = (const float*)d_in[8];
    const float* w_out    = (const float*)d_in[9];
    const float* bn_gamma = (const float*)d_in[10];
    const float* bn_beta  = (const float*)d_in[11];
    const float* bn_mean  = (const float*)d_in[12];
    const float* bn_var   = (const float*)d_in[13];

    float* ws = (float*)d_ws;
    unsigned short* wallbf = (unsigned short*)(ws + OFF_WALLBF);
    float*          ball   = ws + OFF_BALL;
    unsigned short* woutbf = (unsigned short*)(ws + OFF_WOUTBF);
    unsigned short* featT  = (unsigned short*)(ws + OFF_FEATT);
    unsigned short* memT   = (unsigned short*)(ws + OFF_MEMT);
    float*          raw    = ws + OFF_RAW;
    unsigned short* midT   = (unsigned short*)(ws + OFF_MIDT);
    float*          px     = ws + OFF_PX;
    float*          py     = ws + OFF_PY;
    float*          attw   = ws + OFF_ATT;

    pack_w<<<dim3(CO_PAD + C_), dim3(256), 0, stream>>>(
        w_value, b_value, w_size, b_size, w_anchor, b_anchor, w_att, b_att,
        w_out, wallbf, ball, woutbf);
    transpose_feat<<<dim3(L_/32, C_/32, B_), dim3(256), 0, stream>>>(feat, featT);
    gemm_a_mfma<<<dim3(6*96), dim3(256), 0, stream>>>(featT, wallbf, ball, memT, raw);
    post_kernel<<<dim3(B_*L_*NH_/16), dim3(256), 0, stream>>>(raw, px, py, attw);
    sample_kernel<<<dim3(B_*NH_*(L_/32)), dim3(256), 0, stream>>>(memT, px, py, attw, midT);
    gemm_b_mfma<<<dim3(2*96), dim3(256), 0, stream>>>(
        midT, woutbf, bn_gamma, bn_beta, bn_mean, bn_var, (float*)d_out);
}

// Round 4
// 80.262 us; speedup vs baseline: 3.5103x; 2.0156x over previous
//
#include <hip/hip_runtime.h>
#include <math.h>

#define B_ 2
#define C_ 256
#define H_ 64
#define W_ 96
#define L_ (H_*W_)          // 6144
#define NH_ 8
#define NP_ 16
#define HD_ 32
#define NTOT (B_*L_)        // 12288
#define CO_ALL 656
#define CO_PAD 768
#define RAW_CH 400
#define LDK 72              // LDS row stride in bf16 elems (64 + 8 pad)

typedef __attribute__((ext_vector_type(8))) short short8;
typedef __attribute__((ext_vector_type(4))) float f32x4;
typedef __attribute__((ext_vector_type(2))) float f32x2;

// ---- workspace layout (float offsets) ----
#define OFF_WALLBF 0          // 768*256 ushort = 98304 floats
#define OFF_BALL   98304      // 768 floats -> 99072
#define OFF_WOUTBF 99072      // 256*256 ushort = 32768 floats -> 131840
#define OFF_FEATT  131840     // B*L*C ushort = 1572864 floats -> 1704704
#define OFF_MEMT   1704704    // B*NH*L*HD ushort = 1572864 floats -> 3277568
#define OFF_RAW    3277568    // B*400*L floats = 4915200 -> 8192768
#define OFF_MIDT   8192768    // B*L*C ushort = 1572864 floats -> 9765632 (~39.1 MB)

__device__ __forceinline__ float sigmoidf_(float x) { return 1.f / (1.f + expf(-x)); }

__device__ __forceinline__ unsigned short f2bf(float x) {
    union { float f; unsigned int u; } v; v.f = x;
    unsigned int r = (v.u + 0x7fffu + ((v.u >> 16) & 1u)) >> 16;
    return (unsigned short)r;
}

// Pack weights to bf16: wallbf[768][256], ball[768], woutbf[256][256]
__global__ void pack_w(const float* __restrict__ wv, const float* __restrict__ bv,
                       const float* __restrict__ wsz, const float* __restrict__ bsz,
                       const float* __restrict__ wan, const float* __restrict__ ban,
                       const float* __restrict__ wat, const float* __restrict__ bat,
                       const float* __restrict__ wout,
                       unsigned short* __restrict__ wallbf, float* __restrict__ ball,
                       unsigned short* __restrict__ woutbf) {
    int o = blockIdx.x;
    int c = threadIdx.x;
    if (o < CO_PAD) {
        float v = 0.f, bvv = 0.f;
        if (o < 256)      { v = wv [(size_t)o*C_ + c];        bvv = bv [o]; }
        else if (o < 272) { v = wsz[(size_t)(o-256)*C_ + c];  bvv = bsz[o-256]; }
        else if (o < 528) { v = wan[(size_t)(o-272)*C_ + c];  bvv = ban[o-272]; }
        else if (o < 656) { v = wat[(size_t)(o-528)*C_ + c];  bvv = bat[o-528]; }
        wallbf[(size_t)o*C_ + c] = f2bf(v);
        if (c == 0) ball[o] = (o < CO_ALL) ? bvv : 0.f;
    } else {
        int r = o - CO_PAD;
        woutbf[(size_t)r*C_ + c] = f2bf(wout[(size_t)r*C_ + c]);
    }
}

// feat[b][c][l] f32 -> featT[b][l][c] bf16, 32x32 LDS transpose tiles
__global__ __launch_bounds__(256) void transpose_feat(const float* __restrict__ feat,
                                                      unsigned short* __restrict__ featT) {
    __shared__ unsigned short tile[32][36];
    const int l0 = blockIdx.x * 32;
    const int c0 = blockIdx.y * 32;
    const int b  = blockIdx.z;
    const int t = threadIdx.x;
    {
        const int c = t >> 3, l4 = (t & 7) * 4;
        float4 v = *(const float4*)(feat + ((size_t)b*C_ + c0 + c)*L_ + l0 + l4);
        tile[c][l4+0] = f2bf(v.x); tile[c][l4+1] = f2bf(v.y);
        tile[c][l4+2] = f2bf(v.z); tile[c][l4+3] = f2bf(v.w);
    }
    __syncthreads();
    {
        const int l = t >> 3, c4 = (t & 7) * 4;
        ushort4 v;
        v.x = tile[c4+0][l]; v.y = tile[c4+1][l];
        v.z = tile[c4+2][l]; v.w = tile[c4+3][l];
        *(ushort4*)(featT + ((size_t)(b*L_ + l0 + l))*C_ + c0 + c4) = v;
    }
}

// GEMM-A (MFMA): y[b,o,l] = ball[o] + sum_c wall[o,c]*feat[b,c,l]
// o<256 -> memT[b][h][l][d] bf16 ; o in [256,656) -> raw[b][o-256][l] f32
__global__ __launch_bounds__(256) void gemm_a_mfma(const unsigned short* __restrict__ featT,
        const unsigned short* __restrict__ wallbf, const float* __restrict__ ball,
        unsigned short* __restrict__ memT, float* __restrict__ raw) {
    __shared__ short As[128 * LDK];
    __shared__ short Bs[128 * LDK];
    const int gid = blockIdx.x;          // 576 blocks, XCD-chunked
    const int xcd = gid & 7, j = gid >> 3;
    const int yt = xcd * 12 + j / 6;
    const int xt = j % 6;
    const int m0 = xt * 128;
    const int n0 = yt * 128;
    const int b  = n0 / L_, l0 = n0 % L_;
    const int tid = threadIdx.x;
    const int wid = tid >> 6, lane = tid & 63;
    const int wr = wid >> 1, wc = wid & 1;
    const int fr = lane & 15, fg = lane >> 4;
    f32x4 acc[4][4] = {};

    const unsigned short* fT = featT + ((size_t)(b*L_ + l0)) * C_;
    const int sr = tid >> 1;             // staging row 0..127
    const int sko = (tid & 1) * 32;      // k offset 0/32

    for (int k0 = 0; k0 < C_; k0 += 64) {
        const short8* ga = (const short8*)(wallbf + (size_t)(m0 + sr)*C_ + k0 + sko);
        const short8* gb = (const short8*)(fT + (size_t)sr*C_ + k0 + sko);
        short* la = As + sr*LDK + sko;
        short* lb = Bs + sr*LDK + sko;
        #pragma unroll
        for (int q = 0; q < 4; ++q) {
            *(short8*)(la + q*8) = ga[q];
            *(short8*)(lb + q*8) = gb[q];
        }
        __syncthreads();
        #pragma unroll
        for (int kk = 0; kk < 64; kk += 32) {
            short8 af[4], bfm[4];
            #pragma unroll
            for (int m = 0; m < 4; ++m)
                af[m] = *(const short8*)(As + (wr*64 + m*16 + fr)*LDK + kk + fg*8);
            #pragma unroll
            for (int n = 0; n < 4; ++n)
                bfm[n] = *(const short8*)(Bs + (wc*64 + n*16 + fr)*LDK + kk + fg*8);
            #pragma unroll
            for (int m = 0; m < 4; ++m)
                #pragma unroll
                for (int n = 0; n < 4; ++n)
                    acc[m][n] = __builtin_amdgcn_mfma_f32_16x16x32_bf16(af[m], bfm[n], acc[m][n], 0, 0, 0);
        }
        __syncthreads();
    }

    if (m0 < 256) {  // value path: memT[b][h][l][d] bf16
        #pragma unroll
        for (int m = 0; m < 4; ++m) {
            const int ob = m0 + wr*64 + m*16 + fg*4;
            const int h = ob >> 5, d0 = ob & 31;
            const float b0 = ball[ob], b1 = ball[ob+1], b2 = ball[ob+2], b3 = ball[ob+3];
            #pragma unroll
            for (int n = 0; n < 4; ++n) {
                const int l = l0 + wc*64 + n*16 + fr;
                ushort4 v;
                v.x = f2bf(acc[m][n][0] + b0);
                v.y = f2bf(acc[m][n][1] + b1);
                v.z = f2bf(acc[m][n][2] + b2);
                v.w = f2bf(acc[m][n][3] + b3);
                *(ushort4*)(memT + ((size_t)(b*NH_ + h)*L_ + l)*HD_ + d0) = v;
            }
        }
    } else {         // raw path: raw[b][r][l] f32
        #pragma unroll
        for (int m = 0; m < 4; ++m) {
            const int ob = m0 + wr*64 + m*16 + fg*4;
            #pragma unroll
            for (int n = 0; n < 4; ++n) {
                const int l = l0 + wc*64 + n*16 + fr;
                #pragma unroll
                for (int q = 0; q < 4; ++q) {
                    const int r = ob + q - 256;
                    if (r < RAW_CH)
                        raw[((size_t)(b*RAW_CH + r))*L_ + l] = acc[m][n][q] + ball[ob+q];
                }
            }
        }
    }
}

// Fused sampling: phase0 builds per-(l,p) records {off|flags, wx, wy, aw} in LDS
// (absorbs old post_kernel), main loop gathers+combines. XCD-aware block map.
// Lane split: 16 lanes x 2 d's (dword taps) x 4 point-groups.
__global__ __launch_bounds__(256) void sample_kernel(
        const unsigned short* __restrict__ memT,
        const float* __restrict__ raw,
        unsigned short* __restrict__ midT) {
    __shared__ int4 tbl[32][16];
    __shared__ float tile[32][33];
    const int blk = blockIdx.x;
    const int xcd = blk & 7;             // consecutive blockIdx round-robins XCDs
    const int j   = blk >> 3;
    const int half = (j >= (L_/32)) ? 1 : 0;
    const int bh  = xcd * 2 + half;      // each XCD owns 2 of 16 (b,h) slices
    const int lt  = j - half * (L_/32);
    const int h = bh & 7;
    const int b = bh >> 3;
    const int l0 = lt * 32;
    const int tid = threadIdx.x;

    // ---- phase 0: sigmoid/clip/softmax -> LDS records ----
    {
        const int p   = tid & 15;
        const int l16 = tid >> 4;
        const float* rbase = raw + (size_t)b * RAW_CH * L_;
        #pragma unroll
        for (int rep = 0; rep < 2; ++rep) {
            const int lsub = l16 + rep * 16;
            const int l = l0 + lsub;
            const float* rb = rbase + l;
            float sx = fminf(fmaxf(sigmoidf_(rb[(h*2+0)*L_]), 0.25f), 0.75f);
            float sy = fminf(fmaxf(sigmoidf_(rb[(h*2+1)*L_]), 0.25f), 0.75f);
            float cx = ((l % W_) + 0.5f) / ((float)W_ + 1e-6f);
            float cy = ((l / W_) + 0.5f) / ((float)H_ + 1e-6f);
            float ox = sigmoidf_(rb[(16 + h*32 + p*2 + 0)*L_]);
            float oy = sigmoidf_(rb[(16 + h*32 + p*2 + 1)*L_]);
            float gx = fminf(fmaxf(cx - 0.5f*sx + ox*sx, 0.f), 1.f) * (float)(W_-1);
            float gy = fminf(fmaxf(cy - 0.5f*sy + oy*sy, 0.f), 1.f) * (float)(H_-1);
            float a = rb[(272 + h*16 + p)*L_];
            float m = a;
            #pragma unroll
            for (int dd = 8; dd >= 1; dd >>= 1) m = fmaxf(m, __shfl_xor(m, dd, 16));
            float e = expf(a - m);
            float s = e;
            #pragma unroll
            for (int dd = 8; dd >= 1; dd >>= 1) s += __shfl_xor(s, dd, 16);
            float aw = e / s;
            float x0f = floorf(gx), y0f = floorf(gy);
            int x0 = (int)x0f, y0 = (int)y0f;
            unsigned rr = (unsigned)((y0*W_ + x0)*HD_);
            if (x0 < W_-1) rr |= 0x40000000u;   // x1 in range
            if (y0 < H_-1) rr |= 0x80000000u;   // y1 in range
            tbl[lsub][p] = make_int4((int)rr, __float_as_int(gx - x0f),
                                     __float_as_int(gy - y0f), __float_as_int(aw));
        }
    }
    __syncthreads();

    // ---- main: gather + weighted combine ----
    const int wave = tid >> 6, lane = tid & 63;
    const int d2 = lane & 15;            // covers d = 2*d2, 2*d2+1
    const int pg = lane >> 4;            // 0..3, points p = pg*4 + pi
    const uint* vb32 = (const uint*)(memT + (size_t)(b*NH_ + h) * L_ * HD_) + d2;

    #pragma unroll
    for (int li = 0; li < 8; ++li) {
        const int lsub = wave*8 + li;
        f32x2 acc = {0.f, 0.f};
        #pragma unroll
        for (int pi = 0; pi < 4; ++pi) {
            int4 t = tbl[lsub][pg*4 + pi];       // ds_read_b128, broadcast in 16-lane group
            unsigned rr = (unsigned)t.x;
            int off2 = (int)((rr & 0x00FFFFFFu) >> 1);   // dword offset of cell
            int dx2  = (int)((rr >> 26) & 16u);          // +16 dwords if x1 valid
            int dy2  = (t.x >> 31) & 1536;               // +W*HD/2 dwords if y1 valid
            float wx = __int_as_float(t.y);
            float wy = __int_as_float(t.z);
            float aw = __int_as_float(t.w);
            uint u00 = vb32[off2];
            uint u01 = vb32[off2 + dx2];
            uint u10 = vb32[off2 + dy2];
            uint u11 = vb32[off2 + dx2 + dy2];
            float aiy = aw * (1.f - wy), awy = aw * wy;
            float w00 = aiy * (1.f - wx), w01 = aiy * wx;
            float w10 = awy * (1.f - wx), w11 = awy * wx;
            f32x2 v00 = { __uint_as_float(u00 << 16), __uint_as_float(u00 & 0xffff0000u) };
            f32x2 v01 = { __uint_as_float(u01 << 16), __uint_as_float(u01 & 0xffff0000u) };
            f32x2 v10 = { __uint_as_float(u10 << 16), __uint_as_float(u10 & 0xffff0000u) };
            f32x2 v11 = { __uint_as_float(u11 << 16), __uint_as_float(u11 & 0xffff0000u) };
            acc += v00 * w00;
            acc += v01 * w01;
            acc += v10 * w10;
            acc += v11 * w11;
        }
        acc.x += __shfl_xor(acc.x, 16);
        acc.y += __shfl_xor(acc.y, 16);
        acc.x += __shfl_xor(acc.x, 32);
        acc.y += __shfl_xor(acc.y, 32);
        if (pg == 0) { tile[lsub][d2*2] = acc.x; tile[lsub][d2*2+1] = acc.y; }
    }
    __syncthreads();
    {
        const int l = tid >> 3;
        const int c4 = (tid & 7) * 4;
        ushort4 v;
        v.x = f2bf(tile[l][c4+0]); v.y = f2bf(tile[l][c4+1]);
        v.z = f2bf(tile[l][c4+2]); v.w = f2bf(tile[l][c4+3]);
        *(ushort4*)(midT + ((size_t)(b*L_ + l0 + l))*C_ + h*HD_ + c4) = v;
    }
}

// GEMM-B (MFMA): out[b,o,l] = BN( sum_c w_out[o,c] * midT[b,l,c] )
__global__ __launch_bounds__(256) void gemm_b_mfma(const unsigned short* __restrict__ midT,
        const unsigned short* __restrict__ woutbf,
        const float* __restrict__ gamma, const float* __restrict__ beta,
        const float* __restrict__ mean, const float* __restrict__ var,
        float* __restrict__ out) {
    __shared__ short As[128 * LDK];
    __shared__ short Bs[128 * LDK];
    const int gid = blockIdx.x;          // 192 blocks
    const int xcd = gid & 7, j = gid >> 3;
    const int yt = xcd * 12 + j / 2;
    const int xt = j & 1;
    const int m0 = xt * 128;
    const int n0 = yt * 128;
    const int b  = n0 / L_, l0 = n0 % L_;
    const int tid = threadIdx.x;
    const int wid = tid >> 6, lane = tid & 63;
    const int wr = wid >> 1, wc = wid & 1;
    const int fr = lane & 15, fg = lane >> 4;
    f32x4 acc[4][4] = {};

    const unsigned short* mT = midT + ((size_t)(b*L_ + l0)) * C_;
    const int sr = tid >> 1;
    const int sko = (tid & 1) * 32;

    for (int k0 = 0; k0 < C_; k0 += 64) {
        const short8* ga = (const short8*)(woutbf + (size_t)(m0 + sr)*C_ + k0 + sko);
        const short8* gb = (const short8*)(mT + (size_t)sr*C_ + k0 + sko);
        short* la = As + sr*LDK + sko;
        short* lb = Bs + sr*LDK + sko;
        #pragma unroll
        for (int q = 0; q < 4; ++q) {
            *(short8*)(la + q*8) = ga[q];
            *(short8*)(lb + q*8) = gb[q];
        }
        __syncthreads();
        #pragma unroll
        for (int kk = 0; kk < 64; kk += 32) {
            short8 af[4], bfm[4];
            #pragma unroll
            for (int m = 0; m < 4; ++m)
                af[m] = *(const short8*)(As + (wr*64 + m*16 + fr)*LDK + kk + fg*8);
            #pragma unroll
            for (int n = 0; n < 4; ++n)
                bfm[n] = *(const short8*)(Bs + (wc*64 + n*16 + fr)*LDK + kk + fg*8);
            #pragma unroll
            for (int m = 0; m < 4; ++m)
                #pragma unroll
                for (int n = 0; n < 4; ++n)
                    acc[m][n] = __builtin_amdgcn_mfma_f32_16x16x32_bf16(af[m], bfm[n], acc[m][n], 0, 0, 0);
        }
        __syncthreads();
    }

    #pragma unroll
    for (int m = 0; m < 4; ++m) {
        const int ob = m0 + wr*64 + m*16 + fg*4;
        float sc[4], mn[4], bt[4];
        #pragma unroll
        for (int q = 0; q < 4; ++q) {
            const int o = ob + q;
            sc[q] = gamma[o] * rsqrtf(var[o] + 1e-5f);
            mn[q] = mean[o]; bt[q] = beta[o];
        }
        #pragma unroll
        for (int n = 0; n < 4; ++n) {
            const int l = l0 + wc*64 + n*16 + fr;
            #pragma unroll
            for (int q = 0; q < 4; ++q)
                out[(size_t)b*C_*L_ + (size_t)(ob+q)*L_ + l] = (acc[m][n][q] - mn[q])*sc[q] + bt[q];
        }
    }
}

extern "C" void kernel_launch(void* const* d_in, const int* in_sizes, int n_in,
                              void* d_out, int out_size, void* d_ws, size_t ws_size,
                              hipStream_t stream) {
    const float* feat     = (const float*)d_in[0];
    const float* w_size   = (const float*)d_in[1];
    const float* b_size   = (const float*)d_in[2];
    const float* w_anchor = (const float*)d_in[3];
    const float* b_anchor = (const float*)d_in[4];
    const float* w_value  = (const float*)d_in[5];
    const float* b_value  = (const float*)d_in[6];
    const float* w_att    = (const float*)d_in[7];
    const float* b_att    = (const float*)d_in[8];
    const float* w_out    = (const float*)d_in[9];
    const float* bn_gamma = (const float*)d_in[10];
    const float* bn_beta  = (const float*)d_in[11];
    const float* bn_mean  = (const float*)d_in[12];
    const float* bn_var   = (const float*)d_in[13];

    float* ws = (float*)d_ws;
    unsigned short* wallbf = (unsigned short*)(ws + OFF_WALLBF);
    float*          ball   = ws + OFF_BALL;
    unsigned short* woutbf = (unsigned short*)(ws + OFF_WOUTBF);
    unsigned short* featT  = (unsigned short*)(ws + OFF_FEATT);
    unsigned short* memT   = (unsigned short*)(ws + OFF_MEMT);
    float*          raw    = ws + OFF_RAW;
    unsigned short* midT   = (unsigned short*)(ws + OFF_MIDT);

    pack_w<<<dim3(CO_PAD + C_), dim3(256), 0, stream>>>(
        w_value, b_value, w_size, b_size, w_anchor, b_anchor, w_att, b_att,
        w_out, wallbf, ball, woutbf);
    transpose_feat<<<dim3(L_/32, C_/32, B_), dim3(256), 0, stream>>>(feat, featT);
    gemm_a_mfma<<<dim3(6*96), dim3(256), 0, stream>>>(featT, wallbf, ball, memT, raw);
    sample_kernel<<<dim3(B_*NH_*(L_/32)), dim3(256), 0, stream>>>(memT, raw, midT);
    gemm_b_mfma<<<dim3(2*96), dim3(256), 0, stream>>>(
        midT, woutbf, bn_gamma, bn_beta, bn_mean, bn_var, (float*)d_out);
}

// Round 8
// 74.449 us; speedup vs baseline: 3.7844x; 1.0781x over previous
//
#include <hip/hip_runtime.h>
#include <math.h>

#define B_ 2
#define C_ 256
#define H_ 64
#define W_ 96
#define L_ (H_*W_)          // 6144
#define NH_ 8
#define NP_ 16
#define HD_ 32
#define NTOT (B_*L_)        // 12288
#define CO_ALL 656
#define CO_PAD 768
#define RAW_CH 400
#define LDK 72              // LDS row stride in bf16 elems (64 + 8 pad)

typedef __attribute__((ext_vector_type(8))) short short8;
typedef __attribute__((ext_vector_type(4))) float f32x4;
typedef __attribute__((ext_vector_type(2))) float f32x2;

// ---- workspace layout (float offsets) ----
#define OFF_WALLBF 0          // 768*256 ushort = 98304 floats
#define OFF_BALL   98304      // 768 floats -> 99072
#define OFF_WOUTBF 99072      // 256*256 ushort = 32768 floats -> 131840
#define OFF_FEATT  131840     // B*L*C ushort = 1572864 floats -> 1704704
#define OFF_MEMT   1704704    // B*NH*L*HD ushort = 1572864 floats -> 3277568
#define OFF_RAW    3277568    // B*400*L floats = 4915200 -> 8192768
#define OFF_MIDT   8192768    // B*L*C ushort = 1572864 floats -> 9765632 (~39.1 MB)

__device__ __forceinline__ float sigmoidf_(float x) { return 1.f / (1.f + expf(-x)); }

__device__ __forceinline__ unsigned short f2bf(float x) {
    union { float f; unsigned int u; } v; v.f = x;
    unsigned int r = (v.u + 0x7fffu + ((v.u >> 16) & 1u)) >> 16;
    return (unsigned short)r;
}

// Fused prep: blocks [0, CO_PAD+C_) pack weights to bf16; remaining 3072 blocks
// transpose feat[b][c][l] f32 -> featT[b][l][c] bf16 (32x32 LDS tiles).
__global__ __launch_bounds__(256) void prep(
        const float* __restrict__ wv, const float* __restrict__ bv,
        const float* __restrict__ wsz, const float* __restrict__ bsz,
        const float* __restrict__ wan, const float* __restrict__ ban,
        const float* __restrict__ wat, const float* __restrict__ bat,
        const float* __restrict__ wout, const float* __restrict__ feat,
        unsigned short* __restrict__ wallbf, float* __restrict__ ball,
        unsigned short* __restrict__ woutbf, unsigned short* __restrict__ featT) {
    __shared__ unsigned short tile[32][36];
    const int bid = blockIdx.x;
    const int t = threadIdx.x;
    if (bid < CO_PAD + C_) {
        const int o = bid, c = t;
        if (o < CO_PAD) {
            float v = 0.f, bvv = 0.f;
            if (o < 256)      { v = wv [(size_t)o*C_ + c];        bvv = bv [o]; }
            else if (o < 272) { v = wsz[(size_t)(o-256)*C_ + c];  bvv = bsz[o-256]; }
            else if (o < 528) { v = wan[(size_t)(o-272)*C_ + c];  bvv = ban[o-272]; }
            else if (o < 656) { v = wat[(size_t)(o-528)*C_ + c];  bvv = bat[o-528]; }
            wallbf[(size_t)o*C_ + c] = f2bf(v);
            if (c == 0) ball[o] = (o < CO_ALL) ? bvv : 0.f;
        } else {
            int r = o - CO_PAD;
            woutbf[(size_t)r*C_ + c] = f2bf(wout[(size_t)r*C_ + c]);
        }
        return;
    }
    const int tt = bid - (CO_PAD + C_);          // 0..3071
    const int l0 = (tt % (L_/32)) * 32;
    const int c0 = ((tt / (L_/32)) & 7) * 32;
    const int b  = tt / ((L_/32) * 8);
    {
        const int c = t >> 3, l4 = (t & 7) * 4;
        float4 v = *(const float4*)(feat + ((size_t)b*C_ + c0 + c)*L_ + l0 + l4);
        tile[c][l4+0] = f2bf(v.x); tile[c][l4+1] = f2bf(v.y);
        tile[c][l4+2] = f2bf(v.z); tile[c][l4+3] = f2bf(v.w);
    }
    __syncthreads();
    {
        const int l = t >> 3, c4 = (t & 7) * 4;
        ushort4 v;
        v.x = tile[c4+0][l]; v.y = tile[c4+1][l];
        v.z = tile[c4+2][l]; v.w = tile[c4+3][l];
        *(ushort4*)(featT + ((size_t)(b*L_ + l0 + l))*C_ + c0 + c4) = v;
    }
}

// GEMM-A (MFMA): y[b,o,l] = ball[o] + sum_c wall[o,c]*feat[b,c,l]
// o<256 -> memT[b][h][l][d] bf16 ; o in [256,656) -> raw[b][o-256][l] f32
__global__ __launch_bounds__(256) void gemm_a_mfma(const unsigned short* __restrict__ featT,
        const unsigned short* __restrict__ wallbf, const float* __restrict__ ball,
        unsigned short* __restrict__ memT, float* __restrict__ raw) {
    __shared__ short As[128 * LDK];
    __shared__ short Bs[128 * LDK];
    const int gid = blockIdx.x;          // 576 blocks, XCD-chunked
    const int xcd = gid & 7, j = gid >> 3;
    const int yt = xcd * 12 + j / 6;
    const int xt = j % 6;
    const int m0 = xt * 128;
    const int n0 = yt * 128;
    const int b  = n0 / L_, l0 = n0 % L_;
    const int tid = threadIdx.x;
    const int wid = tid >> 6, lane = tid & 63;
    const int wr = wid >> 1, wc = wid & 1;
    const int fr = lane & 15, fg = lane >> 4;
    f32x4 acc[4][4] = {};

    const unsigned short* fT = featT + ((size_t)(b*L_ + l0)) * C_;
    const int sr = tid >> 1;             // staging row 0..127
    const int sko = (tid & 1) * 32;      // k offset 0/32

    for (int k0 = 0; k0 < C_; k0 += 64) {
        const short8* ga = (const short8*)(wallbf + (size_t)(m0 + sr)*C_ + k0 + sko);
        const short8* gb = (const short8*)(fT + (size_t)sr*C_ + k0 + sko);
        short* la = As + sr*LDK + sko;
        short* lb = Bs + sr*LDK + sko;
        #pragma unroll
        for (int q = 0; q < 4; ++q) {
            *(short8*)(la + q*8) = ga[q];
            *(short8*)(lb + q*8) = gb[q];
        }
        __syncthreads();
        #pragma unroll
        for (int kk = 0; kk < 64; kk += 32) {
            short8 af[4], bfm[4];
            #pragma unroll
            for (int m = 0; m < 4; ++m)
                af[m] = *(const short8*)(As + (wr*64 + m*16 + fr)*LDK + kk + fg*8);
            #pragma unroll
            for (int n = 0; n < 4; ++n)
                bfm[n] = *(const short8*)(Bs + (wc*64 + n*16 + fr)*LDK + kk + fg*8);
            #pragma unroll
            for (int m = 0; m < 4; ++m)
                #pragma unroll
                for (int n = 0; n < 4; ++n)
                    acc[m][n] = __builtin_amdgcn_mfma_f32_16x16x32_bf16(af[m], bfm[n], acc[m][n], 0, 0, 0);
        }
        __syncthreads();
    }

    if (m0 < 256) {  // value path: memT[b][h][l][d] bf16
        #pragma unroll
        for (int m = 0; m < 4; ++m) {
            const int ob = m0 + wr*64 + m*16 + fg*4;
            const int h = ob >> 5, d0 = ob & 31;
            const float b0 = ball[ob], b1 = ball[ob+1], b2 = ball[ob+2], b3 = ball[ob+3];
            #pragma unroll
            for (int n = 0; n < 4; ++n) {
                const int l = l0 + wc*64 + n*16 + fr;
                ushort4 v;
                v.x = f2bf(acc[m][n][0] + b0);
                v.y = f2bf(acc[m][n][1] + b1);
                v.z = f2bf(acc[m][n][2] + b2);
                v.w = f2bf(acc[m][n][3] + b3);
                *(ushort4*)(memT + ((size_t)(b*NH_ + h)*L_ + l)*HD_ + d0) = v;
            }
        }
    } else {         // raw path: raw[b][r][l] f32
        #pragma unroll
        for (int m = 0; m < 4; ++m) {
            const int ob = m0 + wr*64 + m*16 + fg*4;
            #pragma unroll
            for (int n = 0; n < 4; ++n) {
                const int l = l0 + wc*64 + n*16 + fr;
                #pragma unroll
                for (int q = 0; q < 4; ++q) {
                    const int r = ob + q - 256;
                    if (r < RAW_CH)
                        raw[((size_t)(b*RAW_CH + r))*L_ + l] = acc[m][n][q] + ball[ob+q];
                }
            }
        }
    }
}

// Fused sampling: phase0 builds per-(l,p) records {off|flags, wx, wy, aw} in LDS,
// main loop gathers+combines. 16 l's per block (6144 blocks, XCD-aware).
// Per l: 64 lanes = 16 d2 x 4 pg, 4 points each (identical summation order to R4).
__global__ __launch_bounds__(256) void sample_kernel(
        const unsigned short* __restrict__ memT,
        const float* __restrict__ raw,
        unsigned short* __restrict__ midT) {
    __shared__ int4 tbl[16][16];
    __shared__ float tile[16][33];
    const int blk = blockIdx.x;          // 6144 = B_*NH_*(L_/16)
    const int xcd = blk & 7;             // consecutive blockIdx round-robins XCDs
    const int j   = blk >> 3;            // 0..767
    const int half = (j >= 384) ? 1 : 0;
    const int bh  = xcd * 2 + half;      // each XCD owns 2 of 16 (b,h) slices
    const int lt  = j - half * 384;
    const int h = bh & 7;
    const int b = bh >> 3;
    const int l0 = lt * 16;
    const int tid = threadIdx.x;

    // ---- phase 0: one record per thread (16 l x 16 p) ----
    {
        const int p    = tid & 15;
        const int lsub = tid >> 4;
        const int l = l0 + lsub;
        const float* rb = raw + (size_t)b * RAW_CH * L_ + l;
        float sx = fminf(fmaxf(sigmoidf_(rb[(h*2+0)*L_]), 0.25f), 0.75f);
        float sy = fminf(fmaxf(sigmoidf_(rb[(h*2+1)*L_]), 0.25f), 0.75f);
        float cx = ((l % W_) + 0.5f) / ((float)W_ + 1e-6f);
        float cy = ((l / W_) + 0.5f) / ((float)H_ + 1e-6f);
        float ox = sigmoidf_(rb[(16 + h*32 + p*2 + 0)*L_]);
        float oy = sigmoidf_(rb[(16 + h*32 + p*2 + 1)*L_]);
        float gx = fminf(fmaxf(cx - 0.5f*sx + ox*sx, 0.f), 1.f) * (float)(W_-1);
        float gy = fminf(fmaxf(cy - 0.5f*sy + oy*sy, 0.f), 1.f) * (float)(H_-1);
        float a = rb[(272 + h*16 + p)*L_];
        float m = a;
        #pragma unroll
        for (int dd = 8; dd >= 1; dd >>= 1) m = fmaxf(m, __shfl_xor(m, dd, 16));
        float e = expf(a - m);
        float s = e;
        #pragma unroll
        for (int dd = 8; dd >= 1; dd >>= 1) s += __shfl_xor(s, dd, 16);
        float aw = e / s;
        float x0f = floorf(gx), y0f = floorf(gy);
        int x0 = (int)x0f, y0 = (int)y0f;
        unsigned rr = (unsigned)((y0*W_ + x0)*HD_);
        if (x0 < W_-1) rr |= 0x40000000u;   // x1 in range
        if (y0 < H_-1) rr |= 0x80000000u;   // y1 in range
        tbl[lsub][p] = make_int4((int)rr, __float_as_int(gx - x0f),
                                 __float_as_int(gy - y0f), __float_as_int(aw));
    }
    __syncthreads();

    // ---- main: gather + weighted combine ----
    const int wave = tid >> 6, lane = tid & 63;
    const int d2 = lane & 15;            // covers d = 2*d2, 2*d2+1
    const int pg = lane >> 4;            // 0..3, points p = pg*4 + pi
    const uint* vb32 = (const uint*)(memT + (size_t)(b*NH_ + h) * L_ * HD_) + d2;

    #pragma unroll
    for (int li = 0; li < 4; ++li) {
        const int lsub = wave*4 + li;
        int4 rec[4];
        #pragma unroll
        for (int pi = 0; pi < 4; ++pi) rec[pi] = tbl[lsub][pg*4 + pi];   // batched ds_read_b128
        f32x2 acc = {0.f, 0.f};
        #pragma unroll
        for (int pi = 0; pi < 4; ++pi) {
            int4 t = rec[pi];
            unsigned rr = (unsigned)t.x;
            int off2 = (int)((rr & 0x00FFFFFFu) >> 1);   // dword offset of cell
            int dx2  = (int)((rr >> 26) & 16u);          // +16 dwords if x1 valid
            int dy2  = (t.x >> 31) & 1536;               // +W*HD/2 dwords if y1 valid
            float wx = __int_as_float(t.y);
            float wy = __int_as_float(t.z);
            float aw = __int_as_float(t.w);
            uint u00 = vb32[off2];
            uint u01 = vb32[off2 + dx2];
            uint u10 = vb32[off2 + dy2];
            uint u11 = vb32[off2 + dx2 + dy2];
            float aiy = aw * (1.f - wy), awy = aw * wy;
            float w00 = aiy * (1.f - wx), w01 = aiy * wx;
            float w10 = awy * (1.f - wx), w11 = awy * wx;
            f32x2 v00 = { __uint_as_float(u00 << 16), __uint_as_float(u00 & 0xffff0000u) };
            f32x2 v01 = { __uint_as_float(u01 << 16), __uint_as_float(u01 & 0xffff0000u) };
            f32x2 v10 = { __uint_as_float(u10 << 16), __uint_as_float(u10 & 0xffff0000u) };
            f32x2 v11 = { __uint_as_float(u11 << 16), __uint_as_float(u11 & 0xffff0000u) };
            acc += v00 * w00;
            acc += v01 * w01;
            acc += v10 * w10;
            acc += v11 * w11;
        }
        acc.x += __shfl_xor(acc.x, 16);
        acc.y += __shfl_xor(acc.y, 16);
        acc.x += __shfl_xor(acc.x, 32);
        acc.y += __shfl_xor(acc.y, 32);
        if (pg == 0) { tile[lsub][d2*2] = acc.x; tile[lsub][d2*2+1] = acc.y; }
    }
    __syncthreads();
    if (tid < 128) {
        const int l = tid >> 3;
        const int c4 = (tid & 7) * 4;
        ushort4 v;
        v.x = f2bf(tile[l][c4+0]); v.y = f2bf(tile[l][c4+1]);
        v.z = f2bf(tile[l][c4+2]); v.w = f2bf(tile[l][c4+3]);
        *(ushort4*)(midT + ((size_t)(b*L_ + l0 + l))*C_ + h*HD_ + c4) = v;
    }
}

// GEMM-B (MFMA): out[b,o,l] = BN( sum_c w_out[o,c] * midT[b,l,c] )
__global__ __launch_bounds__(256) void gemm_b_mfma(const unsigned short* __restrict__ midT,
        const unsigned short* __restrict__ woutbf,
        const float* __restrict__ gamma, const float* __restrict__ beta,
        const float* __restrict__ mean, const float* __restrict__ var,
        float* __restrict__ out) {
    __shared__ short As[128 * LDK];
    __shared__ short Bs[128 * LDK];
    const int gid = blockIdx.x;          // 192 blocks
    const int xcd = gid & 7, j = gid >> 3;
    const int yt = xcd * 12 + j / 2;
    const int xt = j & 1;
    const int m0 = xt * 128;
    const int n0 = yt * 128;
    const int b  = n0 / L_, l0 = n0 % L_;
    const int tid = threadIdx.x;
    const int wid = tid >> 6, lane = tid & 63;
    const int wr = wid >> 1, wc = wid & 1;
    const int fr = lane & 15, fg = lane >> 4;
    f32x4 acc[4][4] = {};

    const unsigned short* mT = midT + ((size_t)(b*L_ + l0)) * C_;
    const int sr = tid >> 1;
    const int sko = (tid & 1) * 32;

    for (int k0 = 0; k0 < C_; k0 += 64) {
        const short8* ga = (const short8*)(woutbf + (size_t)(m0 + sr)*C_ + k0 + sko);
        const short8* gb = (const short8*)(mT + (size_t)sr*C_ + k0 + sko);
        short* la = As + sr*LDK + sko;
        short* lb = Bs + sr*LDK + sko;
        #pragma unroll
        for (int q = 0; q < 4; ++q) {
            *(short8*)(la + q*8) = ga[q];
            *(short8*)(lb + q*8) = gb[q];
        }
        __syncthreads();
        #pragma unroll
        for (int kk = 0; kk < 64; kk += 32) {
            short8 af[4], bfm[4];
            #pragma unroll
            for (int m = 0; m < 4; ++m)
                af[m] = *(const short8*)(As + (wr*64 + m*16 + fr)*LDK + kk + fg*8);
            #pragma unroll
            for (int n = 0; n < 4; ++n)
                bfm[n] = *(const short8*)(Bs + (wc*64 + n*16 + fr)*LDK + kk + fg*8);
            #pragma unroll
            for (int m = 0; m < 4; ++m)
                #pragma unroll
                for (int n = 0; n < 4; ++n)
                    acc[m][n] = __builtin_amdgcn_mfma_f32_16x16x32_bf16(af[m], bfm[n], acc[m][n], 0, 0, 0);
        }
        __syncthreads();
    }

    #pragma unroll
    for (int m = 0; m < 4; ++m) {
        const int ob = m0 + wr*64 + m*16 + fg*4;
        float sc[4], mn[4], bt[4];
        #pragma unroll
        for (int q = 0; q < 4; ++q) {
            const int o = ob + q;
            sc[q] = gamma[o] * rsqrtf(var[o] + 1e-5f);
            mn[q] = mean[o]; bt[q] = beta[o];
        }
        #pragma unroll
        for (int n = 0; n < 4; ++n) {
            const int l = l0 + wc*64 + n*16 + fr;
            #pragma unroll
            for (int q = 0; q < 4; ++q)
                out[(size_t)b*C_*L_ + (size_t)(ob+q)*L_ + l] = (acc[m][n][q] - mn[q])*sc[q] + bt[q];
        }
    }
}

extern "C" void kernel_launch(void* const* d_in, const int* in_sizes, int n_in,
                              void* d_out, int out_size, void* d_ws, size_t ws_size,
                              hipStream_t stream) {
    const float* feat     = (const float*)d_in[0];
    const float* w_size   = (const float*)d_in[1];
    const float* b_size   = (const float*)d_in[2];
    const float* w_anchor = (const float*)d_in[3];
    const float* b_anchor = (const float*)d_in[4];
    const float* w_value  = (const float*)d_in[5];
    const float* b_value  = (const float*)d_in[6];
    const float* w_att    = (const float*)d_in[7];
    const float* b_att    = (const float*)d_in[8];
    const float* w_out    = (const float*)d_in[9];
    const float* bn_gamma = (const float*)d_in[10];
    const float* bn_beta  = (const float*)d_in[11];
    const float* bn_mean  = (const float*)d_in[12];
    const float* bn_var   = (const float*)d_in[13];

    float* ws = (float*)d_ws;
    unsigned short* wallbf = (unsigned short*)(ws + OFF_WALLBF);
    float*          ball   = ws + OFF_BALL;
    unsigned short* woutbf = (unsigned short*)(ws + OFF_WOUTBF);
    unsigned short* featT  = (unsigned short*)(ws + OFF_FEATT);
    unsigned short* memT   = (unsigned short*)(ws + OFF_MEMT);
    float*          raw    = ws + OFF_RAW;
    unsigned short* midT   = (unsigned short*)(ws + OFF_MIDT);

    prep<<<dim3(CO_PAD + C_ + (L_/32)*8*B_), dim3(256), 0, stream>>>(
        w_value, b_value, w_size, b_size, w_anchor, b_anchor, w_att, b_att,
        w_out, feat, wallbf, ball, woutbf, featT);
    gemm_a_mfma<<<dim3(6*96), dim3(256), 0, stream>>>(featT, wallbf, ball, memT, raw);
    sample_kernel<<<dim3(B_*NH_*(L_/16)), dim3(256), 0, stream>>>(memT, raw, midT);
    gemm_b_mfma<<<dim3(2*96), dim3(256), 0, stream>>>(
        midT, woutbf, bn_gamma, bn_beta, bn_mean, bn_var, (float*)d_out);
}